// Round 9
// baseline (501.141 us; speedup 1.0000x reference)
//
#include <hip/hip_runtime.h>
#include <hip/hip_bf16.h>

#define NN 50000
#define EE 1000000
#define NGRAPHS 64
#define OUTD 100
#define NB_N 196        // (NN+255)/256
#define NB_E 3907       // (EE+255)/256
#define NTAB 4096
#define SPL 16          // reduction splits per graph

#define INV_SQRT_NEIGH 0.22360679774997896f   // 1/sqrt(20)
#define INV_SQRT_NODES 0.035777087639996634f  // 1/sqrt(781.25)
#define SQRT3 1.7320508075688772f
#define BSCALE 2.8234621879136734f            // sqrt(10)/1.12
#define BSTEP 0.3888888888888889f             // 3.5/9
#define INV_BSTEP 2.5714285714285716f
#define PI_F 3.14159265358979323846f
#define TAB_DR (3.5f / 4095.0f)
#define TAB_SCALE (4095.0f / 3.5f)

__device__ __forceinline__ float silu_f(float x) { return x / (1.0f + __expf(-x)); }
__device__ __forceinline__ float sigm_f(float x) { return 1.0f / (1.0f + __expf(-x)); }

__device__ __forceinline__ unsigned short f2bf(float f) {
    union { float f; unsigned u; } v; v.f = f;
    unsigned r = v.u + 0x7fffu + ((v.u >> 16) & 1u);
    return (unsigned short)(r >> 16);
}
__device__ __forceinline__ float bf2f(unsigned short u) {
    return __uint_as_float((unsigned)u << 16);
}

// ================= combined prologue: radial tables + graph bounds + degree hist =================
// blocks [0,256): tables; [256,452): graph bounds; [452,4359): histogram
__global__ __launch_bounds__(256) void k_pre(
    const float* __restrict__ fc1w0, const float* __restrict__ fc1w1,
    const float* __restrict__ fc2w0, const float* __restrict__ fc2w1,
    const float* __restrict__ fcow0, const float* __restrict__ fcow1,
    float* __restrict__ tab1, unsigned short* __restrict__ tab2b,
    unsigned short* __restrict__ tab3b,
    const int* __restrict__ batch, int* __restrict__ gstart,
    const int* __restrict__ ei, int* __restrict__ deg)
{
    int blk = blockIdx.x;
    if (blk < 256) {
        int tid = blk * 256 + threadIdx.x;   // < NTAB*16
        int entry = tid >> 4, sub = tid & 15;
        float r = entry * TAB_DR;
        float b[10];
#pragma unroll
        for (int i = 0; i < 10; ++i) {
            float d = (r - (float)i * BSTEP) * INV_BSTEP;
            b[i] = __expf(-d * d) * BSCALE;
        }
        const float *w0, *w1p; int K, o0;
        if (sub < 2)       { w0 = fc1w0; w1p = fc1w1; K = 32;  o0 = sub * 16; }
        else if (sub < 12) { w0 = fc2w0; w1p = fc2w1; K = 160; o0 = (sub - 2) * 16; }
        else               { w0 = fcow0; w1p = fcow1; K = 64;  o0 = (sub - 12) * 16; }
        float acc[16];
#pragma unroll
        for (int t = 0; t < 16; ++t) acc[t] = 0.0f;
        for (int j = 0; j < 100; ++j) {
            float hj = 0.0f;
#pragma unroll
            for (int i = 0; i < 10; ++i) hj += b[i] * w0[i * 100 + j];
            hj = silu_f(hj);
            const float* wr = w1p + j * K + o0;
#pragma unroll
            for (int t = 0; t < 16; ++t) acc[t] += hj * wr[t];
        }
        if (sub < 2) {
#pragma unroll
            for (int t = 0; t < 16; ++t) tab1[(size_t)entry * 32 + o0 + t] = acc[t];
        } else if (sub < 12) {
#pragma unroll
            for (int t = 0; t < 16; ++t) {
                int o = o0 + t;
                tab2b[((size_t)entry * 32 + (o & 31)) * 8 + (o >> 5)] = f2bf(acc[t]);
            }
        } else {
#pragma unroll
            for (int t = 0; t < 16; ++t) {
                int o = o0 + t;
                tab3b[((size_t)entry * 32 + (o & 31)) * 2 + (o >> 5)] = f2bf(acc[t]);
            }
        }
    } else if (blk < 256 + NB_N) {
        int n = (blk - 256) * 256 + threadIdx.x;
        if (n >= NN) return;
        int b = batch[n];
        if (n == 0) { for (int g = 0; g <= b; ++g) gstart[g] = 0; }
        else {
            int pb = batch[n - 1];
            for (int g = pb + 1; g <= b; ++g) gstart[g] = n;
        }
        if (n == NN - 1) { for (int g = b + 1; g <= NGRAPHS; ++g) gstart[g] = NN; }
    } else {
        int e = (blk - 256 - NB_N) * 256 + threadIdx.x;
        if (e < EE) atomicAdd(&deg[ei[EE + e]], 1);
    }
}

// ================= CSR scans =================
__global__ __launch_bounds__(256) void k_scan1(const int* __restrict__ deg, int* __restrict__ bsum)
{
    __shared__ int sd[256];
    int t = threadIdx.x;
    int i = blockIdx.x * 256 + t;
    sd[t] = (i < NN) ? deg[i] : 0;
    __syncthreads();
#pragma unroll
    for (int o = 128; o > 0; o >>= 1) {
        if (t < o) sd[t] += sd[t + o];
        __syncthreads();
    }
    if (t == 0) bsum[blockIdx.x] = sd[0];
}

__global__ void k_scan2(const int* __restrict__ bsum, int* __restrict__ boff, int* __restrict__ rowp)
{
    if (threadIdx.x == 0) {
        int acc = 0;
        for (int b = 0; b < NB_N; ++b) { boff[b] = acc; acc += bsum[b]; }
        rowp[NN] = EE;
    }
}

__global__ __launch_bounds__(256) void k_scan3(
    const int* __restrict__ deg, const int* __restrict__ boff,
    int* __restrict__ rowp, int* __restrict__ cursor)
{
    __shared__ int sd[256];
    int t = threadIdx.x;
    int i = blockIdx.x * 256 + t;
    int v = (i < NN) ? deg[i] : 0;
    sd[t] = v;
    __syncthreads();
#pragma unroll
    for (int o = 1; o < 256; o <<= 1) {
        int xv = 0;
        if (t >= o) xv = sd[t - o];
        __syncthreads();
        sd[t] += xv;
        __syncthreads();
    }
    if (i < NN) {
        int val = boff[blockIdx.x] + sd[t] - v;   // exclusive
        rowp[i] = val;
        cursor[i] = val;
    }
}

// ---- per-edge geometry once, scattered to dst-sorted slot (24 B/slot) ----
__global__ __launch_bounds__(256) void k_geom(
    const float* __restrict__ pos, const int* __restrict__ ei,
    const float* __restrict__ eshift, const float* __restrict__ lat,
    const int* __restrict__ batch, int* __restrict__ cursor,
    float4* __restrict__ geo4, float2* __restrict__ grs)
{
    int e = blockIdx.x * 256 + threadIdx.x;
    if (e >= EE) return;
    int src = ei[e];
    int dst = ei[EE + e];
    int g = batch[src];
    const float* L = lat + g * 9;
    float t0 = eshift[e*3+0], t1 = eshift[e*3+1], t2 = eshift[e*3+2];
    float vx = pos[dst*3+0] - pos[src*3+0] + t0*L[0] + t1*L[3] + t2*L[6];
    float vy = pos[dst*3+1] - pos[src*3+1] + t0*L[1] + t1*L[4] + t2*L[7];
    float vz = pos[dst*3+2] - pos[src*3+2] + t0*L[2] + t1*L[5] + t2*L[8];
    float r = sqrtf(vx*vx + vy*vy + vz*vz);
    float u = 2.0f * (r * (1.0f/3.5f) - 1.0f);
    float cut;
    if (u > 0.0f) cut = 0.0f;
    else if (u < -2.0f) cut = 1.0f;
    else cut = 0.5f * (1.0f - __cosf(PI_F * u));
    float inv = 1.0f / fmaxf(r, 1e-12f);
    float sc = SQRT3 * cut * inv;
    float t = fminf(r * TAB_SCALE + 0.5f, 4095.0f);
    int slot = atomicAdd(&cursor[dst], 1);
    geo4[slot] = make_float4(cut, sc * vx, sc * vy, sc * vz);
    grs[slot]  = make_float2(t, __int_as_float(src));
}

// ================= fused node-centric edge kernels (1 wave = 1 dst node) =================
// layer 1: 64 outputs: lane = q*16+c, q=0:ms, q=1..3:mv{x,y,z}; 4-edge unroll
#define F1_EDGE(G, R, ACC) {                                        \
    int i0_ = (int)(R).x;                                           \
    int src_ = __float_as_int((R).y);                               \
    float w_ = tab1[(size_t)i0_ * 32 + toff];                       \
    float xs_ = x[src_ * 16 + c];                                   \
    float gs_ = (q == 0) ? (G).x : (q == 1 ? (G).y : (q == 2 ? (G).z : (G).w)); \
    ACC += w_ * xs_ * gs_; }

__global__ __launch_bounds__(256) void k_fuse1(
    const int* __restrict__ rowp, const float4* __restrict__ geo4,
    const float2* __restrict__ grs, const float* __restrict__ tab1,
    const float* __restrict__ x, float* __restrict__ a1)
{
    int wid = (blockIdx.x * 256 + threadIdx.x) >> 6;
    int l = threadIdx.x & 63;
    if (wid >= NN) return;
    int b0 = __builtin_amdgcn_readfirstlane(rowp[wid]);
    int b1 = __builtin_amdgcn_readfirstlane(rowp[wid + 1]);
    int q = l >> 4, c = l & 15;
    int toff = (q ? 16 : 0) + c;
    float aA = 0.0f, aB = 0.0f, aC = 0.0f, aD = 0.0f;
    int s = b0;
    for (; s + 3 < b1; s += 4) {
        float4 gA = geo4[s], gB = geo4[s+1], gC = geo4[s+2], gD = geo4[s+3];
        float2 rA = grs[s],  rB = grs[s+1],  rC = grs[s+2],  rD = grs[s+3];
        F1_EDGE(gA, rA, aA) F1_EDGE(gB, rB, aB)
        F1_EDGE(gC, rC, aC) F1_EDGE(gD, rD, aD)
    }
    for (; s < b1; ++s) {
        float4 gA = geo4[s]; float2 rA = grs[s];
        F1_EDGE(gA, rA, aA)
    }
    a1[(size_t)wid * 64 + l] = (aA + aB) + (aC + aD);
}

// layer 2: parity halves own even/odd edges; packed loads:
// tab2b row: [32] x uint4 (8 bf16, w1..w5 used); row1: [32] x ushort4 {s,vx,vy,vz}
#define F2_EDGE(G, R, AS, AX, AY, AZ) {                             \
    float cs_ = (G).x;                                              \
    if (cs_ != 0.0f) {                                              \
        int i0_ = (int)(R).x;                                       \
        int src_ = __float_as_int((R).y);                           \
        uint4 tv_ = ((const uint4*)tab2b)[(size_t)i0_ * 32 + c];    \
        ushort4 rv_ = ((const ushort4*)row1)[(size_t)src_ * 32 + c];\
        float w1_ = bf2f((unsigned short)(tv_.x & 0xffffu));        \
        float w2_ = bf2f((unsigned short)(tv_.x >> 16));            \
        float w3_ = bf2f((unsigned short)(tv_.y & 0xffffu));        \
        float w4_ = bf2f((unsigned short)(tv_.y >> 16));            \
        float w5_ = bf2f((unsigned short)(tv_.z & 0xffffu));        \
        float sv_ = bf2f(rv_.x);                                    \
        float vx_ = bf2f(rv_.y), vy_ = bf2f(rv_.z), vz_ = bf2f(rv_.w); \
        float cx_ = (G).y, cy_ = (G).z, cz_ = (G).w;                \
        float dot_ = vx_ * cx_ + vy_ * cy_ + vz_ * cz_;             \
        float w3s_ = w3_ * sv_, w4c_ = w4_ * cs_;                   \
        AS += w1_ * sv_ * cs_ + w2_ * dot_;                         \
        AX += w3s_ * cx_ + w4c_ * vx_ + w5_ * (vy_ * cz_ - vz_ * cy_); \
        AY += w3s_ * cy_ + w4c_ * vy_ + w5_ * (vz_ * cx_ - vx_ * cz_); \
        AZ += w3s_ * cz_ + w4c_ * vz_ + w5_ * (vx_ * cy_ - vy_ * cx_); \
    } }

__global__ __launch_bounds__(256) void k_fuse2(
    const int* __restrict__ rowp, const float4* __restrict__ geo4,
    const float2* __restrict__ grs, const unsigned short* __restrict__ tab2b,
    const unsigned short* __restrict__ row1,
    float* __restrict__ a2)
{
    int wid = (blockIdx.x * 256 + threadIdx.x) >> 6;
    int l = threadIdx.x & 63;
    if (wid >= NN) return;
    int b0 = __builtin_amdgcn_readfirstlane(rowp[wid]);
    int b1 = __builtin_amdgcn_readfirstlane(rowp[wid + 1]);
    int p = l >> 5, c = l & 31;
    float sA = 0, xA = 0, yA = 0, zA = 0;
    float sB = 0, xB = 0, yB = 0, zB = 0;
    int s = b0 + p;
    for (; s + 2 < b1; s += 4) {
        float4 gA = geo4[s], gB = geo4[s+2];
        float2 rA = grs[s],  rB = grs[s+2];
        F2_EDGE(gA, rA, sA, xA, yA, zA)
        F2_EDGE(gB, rB, sB, xB, yB, zB)
    }
    for (; s < b1; s += 2) {
        float4 gA = geo4[s]; float2 rA = grs[s];
        F2_EDGE(gA, rA, sA, xA, yA, zA)
    }
    float mS = sA + sB, mX = xA + xB, mY = yA + yB, mZ = zA + zB;
    mS += __shfl_xor(mS, 32);
    mX += __shfl_xor(mX, 32);
    mY += __shfl_xor(mY, 32);
    mZ += __shfl_xor(mZ, 32);
    if (p == 0) {
        float* ap = a2 + (size_t)wid * 128;
        ap[c]      = mS;
        ap[32 + c] = mX;
        ap[64 + c] = mY;
        ap[96 + c] = mZ;
    }
}

// output layer: tab3b row: [32] x uint (2 bf16); row2: [32] x ushort4 {s,vx,vy,vz}
#define F3_EDGE(G, R, ACC) {                                        \
    float cs_ = (G).x;                                              \
    if (cs_ != 0.0f) {                                              \
        int i0_ = (int)(R).x;                                       \
        int src_ = __float_as_int((R).y);                           \
        unsigned tv_ = ((const unsigned*)tab3b)[(size_t)i0_ * 32 + c]; \
        ushort4 rv_ = ((const ushort4*)row2)[(size_t)src_ * 32 + c];\
        float w1_ = bf2f((unsigned short)(tv_ & 0xffffu));          \
        float w2_ = bf2f((unsigned short)(tv_ >> 16));              \
        float sv_ = bf2f(rv_.x);                                    \
        float dot_ = bf2f(rv_.y) * (G).y + bf2f(rv_.z) * (G).z + bf2f(rv_.w) * (G).w; \
        ACC += w1_ * sv_ * cs_ + w2_ * dot_;                        \
    } }

__global__ __launch_bounds__(256) void k_fuse3(
    const int* __restrict__ rowp, const float4* __restrict__ geo4,
    const float2* __restrict__ grs, const unsigned short* __restrict__ tab3b,
    const unsigned short* __restrict__ row2,
    float* __restrict__ a3)
{
    int wid = (blockIdx.x * 256 + threadIdx.x) >> 6;
    int l = threadIdx.x & 63;
    if (wid >= NN) return;
    int b0 = __builtin_amdgcn_readfirstlane(rowp[wid]);
    int b1 = __builtin_amdgcn_readfirstlane(rowp[wid + 1]);
    int p = l >> 5, c = l & 31;
    float aA = 0.0f, aB = 0.0f;
    int s = b0 + p;
    for (; s + 2 < b1; s += 4) {
        float4 gA = geo4[s], gB = geo4[s+2];
        float2 rA = grs[s],  rB = grs[s+2];
        F3_EDGE(gA, rA, aA)
        F3_EDGE(gB, rB, aB)
    }
    for (; s < b1; s += 2) {
        float4 gA = geo4[s]; float2 rA = grs[s];
        F3_EDGE(gA, rA, aA)
    }
    float acc = aA + aB;
    acc += __shfl_xor(acc, 32);
    if (p == 0) a3[(size_t)wid * 32 + c] = acc;
}

// ================= node kernels =================
// a1 layout per node (64 floats): [ms 16][mvx 16][mvy 16][mvz 16]
__global__ __launch_bounds__(256) void k_node1(
    const float* __restrict__ x, const float* __restrict__ z,
    const float* __restrict__ a1,
    const float* __restrict__ sc1, const float* __restrict__ lin1s,
    const float* __restrict__ lin1v,
    float* __restrict__ s1, float* __restrict__ v1,
    ushort4* __restrict__ row1)
{
    int n = blockIdx.x * 256 + threadIdx.x;
    if (n >= NN) return;
    float zz = z[n];
    float xs[16], as[16];
#pragma unroll
    for (int c = 0; c < 16; ++c) {
        xs[c] = x[n * 16 + c] * zz;
        as[c] = a1[n * 64 + c] * INV_SQRT_NEIGH;
    }
    float sh[64];
#pragma unroll
    for (int o = 0; o < 64; ++o) sh[o] = 0.0f;
    for (int c = 0; c < 16; ++c) {
        float xc = xs[c], ac = as[c];
#pragma unroll
        for (int o = 0; o < 64; ++o)
            sh[o] += xc * sc1[c * 64 + o] + ac * lin1s[c * 64 + o];
    }
    float sout[32], gate[32];
#pragma unroll
    for (int o = 0; o < 32; ++o) {
        sout[o] = silu_f(sh[o]);
        s1[n * 32 + o] = sout[o];
        gate[o] = sigm_f(sh[32 + o]);
    }
    float vout[3][32];
#pragma unroll
    for (int i = 0; i < 3; ++i) {
        float av[16];
#pragma unroll
        for (int c = 0; c < 16; ++c) av[c] = a1[n * 64 + 16 + i * 16 + c] * INV_SQRT_NEIGH;
        float vh[32];
#pragma unroll
        for (int o = 0; o < 32; ++o) vh[o] = 0.0f;
        for (int c = 0; c < 16; ++c) {
            float ac = av[c];
#pragma unroll
            for (int o = 0; o < 32; ++o) vh[o] += ac * lin1v[c * 32 + o];
        }
#pragma unroll
        for (int o = 0; o < 32; ++o) {
            float v = vh[o] * gate[o];
            v1[(n * 3 + i) * 32 + o] = v;
            vout[i][o] = v;
        }
    }
    ushort4* rp = row1 + (size_t)n * 32;
#pragma unroll
    for (int o = 0; o < 32; ++o)
        rp[o] = make_ushort4(f2bf(sout[o]), f2bf(vout[0][o]), f2bf(vout[1][o]), f2bf(vout[2][o]));
}

// a2 layout per node (128 floats): [ms 32][mvx 32][mvy 32][mvz 32]
__global__ __launch_bounds__(256) void k_node2(
    const float* __restrict__ z,
    const float* __restrict__ s1, const float* __restrict__ v1,
    const float* __restrict__ a2,
    const float* __restrict__ sc2s, const float* __restrict__ sc2v,
    const float* __restrict__ lin2s, const float* __restrict__ lin2v,
    float* __restrict__ s2, ushort4* __restrict__ row2)
{
    int n = blockIdx.x * 256 + threadIdx.x;
    if (n >= NN) return;
    float zz = z[n];
    float sv[32], as[32];
#pragma unroll
    for (int c = 0; c < 32; ++c) {
        sv[c] = s1[n * 32 + c] * zz;
        as[c] = a2[(size_t)n * 128 + c] * INV_SQRT_NEIGH;
    }
    float sh[64];
#pragma unroll
    for (int o = 0; o < 64; ++o) sh[o] = 0.0f;
    for (int c = 0; c < 32; ++c) {
        float a = sv[c], d = as[c];
#pragma unroll
        for (int o = 0; o < 64; ++o)
            sh[o] += a * sc2s[c * 64 + o] + d * lin2s[c * 64 + o];
    }
    float sout[32], gate[32];
#pragma unroll
    for (int o = 0; o < 32; ++o) {
        sout[o] = silu_f(sh[o]);
        s2[n * 32 + o] = sout[o];
        gate[o] = sigm_f(sh[32 + o]);
    }
    float vout[3][32];
#pragma unroll
    for (int i = 0; i < 3; ++i) {
        float vv[32], av[32];
#pragma unroll
        for (int c = 0; c < 32; ++c) {
            vv[c] = v1[(n * 3 + i) * 32 + c];
            av[c] = a2[(size_t)n * 128 + 32 + i * 32 + c] * INV_SQRT_NEIGH;
        }
        float vh[32];
#pragma unroll
        for (int o = 0; o < 32; ++o) vh[o] = 0.0f;
        for (int c = 0; c < 32; ++c) {
            float a = vv[c], d = av[c];
#pragma unroll
            for (int o = 0; o < 32; ++o)
                vh[o] += a * sc2v[c * 32 + o] + d * lin2v[c * 32 + o];
        }
#pragma unroll
        for (int o = 0; o < 32; ++o) vout[i][o] = vh[o] * gate[o];
    }
    ushort4* rp = row2 + (size_t)n * 32;
#pragma unroll
    for (int o = 0; o < 32; ++o)
        rp[o] = make_ushort4(f2bf(sout[o]), f2bf(vout[0][o]), f2bf(vout[1][o]), f2bf(vout[2][o]));
}

// ---- output stage 1: per-(graph,split) partial sums of [s2*z | a3] ----
__global__ __launch_bounds__(256) void k_red(
    const float* __restrict__ z, const int* __restrict__ gstart,
    const float* __restrict__ s2, const float* __restrict__ a3,
    float* __restrict__ pbuf)
{
    int g  = blockIdx.x >> 4;      // / SPL
    int sp = blockIdx.x & (SPL - 1);
    int n0 = gstart[g], n1 = gstart[g + 1];
    int per = (n1 - n0 + SPL - 1) / SPL;
    int a = n0 + sp * per;
    int b = a + per; if (b > n1) b = n1;
    int t = threadIdx.x;
    int comp = t & 63;
    int lane = t >> 6;
    float acc = 0.0f;
    for (int n = a + lane; n < b; n += 4) {
        if (comp < 32) acc += s2[n * 32 + comp] * z[n];
        else           acc += a3[(size_t)n * 32 + (comp - 32)];
    }
    __shared__ float sd[256];
    sd[t] = acc;
    __syncthreads();
    if (t < 64)
        pbuf[(size_t)blockIdx.x * 64 + t] = sd[t] + sd[t + 64] + sd[t + 128] + sd[t + 192];
}

// ---- output stage 2: fold partials + (64,32)@(32,100) GEMM ----
__global__ __launch_bounds__(128) void k_out2(
    const float* __restrict__ pbuf, const float* __restrict__ sco,
    const float* __restrict__ lino, float* __restrict__ out)
{
    __shared__ float A[32], B[32];
    int g = blockIdx.x;
    int t = threadIdx.x;
    if (t < 64) {
        float v = 0.0f;
        for (int sp = 0; sp < SPL; ++sp)
            v += pbuf[(size_t)(g * SPL + sp) * 64 + t];
        if (t < 32) A[t] = v;
        else        B[t - 32] = v * INV_SQRT_NEIGH;
    }
    __syncthreads();
    if (t < 100) {
        float res = 0.0f;
#pragma unroll
        for (int c = 0; c < 32; ++c)
            res += A[c] * sco[c * 100 + t] + B[c] * lino[c * 100 + t];
        out[g * 100 + t] = res * INV_SQRT_NODES;
    }
}

// ================= launcher =================
extern "C" void kernel_launch(void* const* d_in, const int* in_sizes, int n_in,
                              void* d_out, int out_size, void* d_ws, size_t ws_size,
                              hipStream_t stream)
{
    const float* pos   = (const float*)d_in[0];
    const float* x     = (const float*)d_in[1];
    const float* z     = (const float*)d_in[2];
    const int*   ei    = (const int*)d_in[3];
    const float* esh   = (const float*)d_in[4];
    const float* lat   = (const float*)d_in[5];
    const int*   batch = (const int*)d_in[6];
    const float* fc1w0 = (const float*)d_in[7];
    const float* fc1w1 = (const float*)d_in[8];
    const float* sc1   = (const float*)d_in[9];
    const float* lin1s = (const float*)d_in[10];
    const float* lin1v = (const float*)d_in[11];
    const float* fc2w0 = (const float*)d_in[12];
    const float* fc2w1 = (const float*)d_in[13];
    const float* sc2s  = (const float*)d_in[14];
    const float* sc2v  = (const float*)d_in[15];
    const float* lin2s = (const float*)d_in[16];
    const float* lin2v = (const float*)d_in[17];
    const float* fcow0 = (const float*)d_in[18];
    const float* fcow1 = (const float*)d_in[19];
    const float* sco   = (const float*)d_in[20];
    const float* lino  = (const float*)d_in[21];
    float* out = (float*)d_out;

    char* cur = (char*)d_ws;
    auto alloc = [&](size_t bytes) { char* r = cur; cur += (bytes + 15) & ~(size_t)15; return r; };

    float* a1    = (float*)alloc((size_t)NN * 64 * 4);
    float* a2    = (float*)alloc((size_t)NN * 128 * 4);
    float* a3    = (float*)alloc((size_t)NN * 32 * 4);
    float* s1    = (float*)alloc((size_t)NN * 32 * 4);
    float* v1    = (float*)alloc((size_t)NN * 96 * 4);
    float* s2    = (float*)alloc((size_t)NN * 32 * 4);
    ushort4* row1 = (ushort4*)alloc((size_t)NN * 32 * 8);
    ushort4* row2 = (ushort4*)alloc((size_t)NN * 32 * 8);
    float* tab1  = (float*)alloc((size_t)NTAB * 32 * 4);
    unsigned short* tab2b = (unsigned short*)alloc((size_t)NTAB * 32 * 8 * 2);
    unsigned short* tab3b = (unsigned short*)alloc((size_t)NTAB * 32 * 2 * 2);
    float* pbuf  = (float*)alloc((size_t)NGRAPHS * SPL * 64 * 4);
    int* deg     = (int*)alloc((size_t)NN * 4);
    int* rowp    = (int*)alloc((size_t)(NN + 4) * 4);
    int* cursor  = (int*)alloc((size_t)NN * 4);
    int* bsum    = (int*)alloc(256 * 4);
    int* boff    = (int*)alloc(256 * 4);
    int* gstart  = (int*)alloc(68 * 4);
    float4* geo4 = (float4*)alloc((size_t)EE * 16);
    float2* grs  = (float2*)alloc((size_t)EE * 8);

    (void)hipMemsetAsync(deg, 0, (size_t)NN * 4, stream);

    // tables + graph bounds + degree histogram in one dispatch
    k_pre<<<256 + NB_N + NB_E, 256, 0, stream>>>(
        fc1w0, fc1w1, fc2w0, fc2w1, fcow0, fcow1, tab1, tab2b, tab3b,
        batch, gstart, ei, deg);

    k_scan1<<<NB_N, 256, 0, stream>>>(deg, bsum);
    k_scan2<<<1, 64, 0, stream>>>(bsum, boff, rowp);
    k_scan3<<<NB_N, 256, 0, stream>>>(deg, boff, rowp, cursor);
    k_geom <<<NB_E, 256, 0, stream>>>(pos, ei, esh, lat, batch, cursor, geo4, grs);

    int fb = (NN * 64 + 255) / 256;   // 1 wave per node
    k_fuse1<<<fb, 256, 0, stream>>>(rowp, geo4, grs, tab1, x, a1);
    k_node1<<<NB_N, 256, 0, stream>>>(x, z, a1, sc1, lin1s, lin1v, s1, v1, row1);
    k_fuse2<<<fb, 256, 0, stream>>>(rowp, geo4, grs, tab2b, (const unsigned short*)row1, a2);
    k_node2<<<NB_N, 256, 0, stream>>>(z, s1, v1, a2, sc2s, sc2v, lin2s, lin2v, s2, row2);
    k_fuse3<<<fb, 256, 0, stream>>>(rowp, geo4, grs, tab3b, (const unsigned short*)row2, a3);
    k_red<<<NGRAPHS * SPL, 256, 0, stream>>>(z, gstart, s2, a3, pbuf);
    k_out2<<<NGRAPHS, 128, 0, stream>>>(pbuf, sco, lino, out);
}